// Round 2
// baseline (89.952 us; speedup 1.0000x reference)
//
#include <hip/hip_runtime.h>
#include <math.h>

#define BLOCK 256
#define WPB   (BLOCK / 64)   // waves per block = 4
#define K     2048
#define ROWS_PER_WAVE 2

// Each wave computes ssq of ROWS_PER_WAVE adjacent rows with interleaved
// loads, butterfly-reduces, block-combines in LDS, then device-scope
// atomicAdd into ws accumulator. Last block applies sqrt -> d_out.
__global__ __launch_bounds__(BLOCK) void row_ssq_fused_kernel(
    const float* __restrict__ d, float* __restrict__ ws_acc,
    unsigned int* __restrict__ ws_cnt, float* __restrict__ out) {
    const int wave  = threadIdx.x >> 6;
    const int lane  = threadIdx.x & 63;
    const int gwave = blockIdx.x * WPB + wave;

    const float4* __restrict__ pa =
        reinterpret_cast<const float4*>(d + (size_t)(2 * gwave) * K);
    const float4* __restrict__ pb =
        reinterpret_cast<const float4*>(d + (size_t)(2 * gwave + 1) * K);

    float sa = 0.0f, sb = 0.0f;
#pragma unroll
    for (int i = 0; i < (K >> 2); i += 64) {   // 8 iters, 2 rows interleaved
        float4 va = pa[i + lane];
        float4 vb = pb[i + lane];
        sa += va.x * va.x + va.y * va.y + va.z * va.z + va.w * va.w;
        sb += vb.x * vb.x + vb.y * vb.y + vb.z * vb.z + vb.w * vb.w;
    }

#pragma unroll
    for (int off = 32; off >= 1; off >>= 1) {
        sa += __shfl_xor(sa, off);
        sb += __shfl_xor(sb, off);
    }

    __shared__ float smem[WPB];
    if (lane == 0) {
        float ta = sa - 1.0f, tb = sb - 1.0f;
        smem[wave] = ta * ta + tb * tb;
    }
    __syncthreads();

    if (threadIdx.x == 0) {
        float b = smem[0] + smem[1] + smem[2] + smem[3];
        atomicAdd(ws_acc, b);                       // device-scope by default
        __threadfence();
        unsigned int prev = atomicAdd(ws_cnt, 1u);
        if (prev == gridDim.x - 1) {                // last block to arrive
            float total = atomicAdd(ws_acc, 0.0f);  // atomic read, sees all adds
            out[0] = 0.001f * sqrtf(total);
        }
    }
}

extern "C" void kernel_launch(void* const* d_in, const int* in_sizes, int n_in,
                              void* d_out, int out_size, void* d_ws, size_t ws_size,
                              hipStream_t stream) {
    const float* d = (const float*)d_in[0];
    float* out = (float*)d_out;
    float* ws_acc = (float*)d_ws;
    unsigned int* ws_cnt = (unsigned int*)d_ws + 1;

    const int n = in_sizes[0] / K;                       // 16384 rows
    const int grid = n / (WPB * ROWS_PER_WAVE);          // 2048 blocks

    hipMemsetAsync(d_ws, 0, 2 * sizeof(float), stream);  // zero acc + counter
    row_ssq_fused_kernel<<<grid, BLOCK, 0, stream>>>(d, ws_acc, ws_cnt, out);
}

// Round 3
// 29.805 us; speedup vs baseline: 3.0180x; 3.0180x over previous
//
#include <hip/hip_runtime.h>
#include <math.h>

#define BLOCK 256
#define WPB   (BLOCK / 64)   // 4 waves per block
#define K     2048

// Phase 1: one wave per row. 8 float4 loads issued back-to-back (clustered,
// all in flight before first use), then reduce. Plain store of one partial
// per block — no atomics, no fences (R2 showed same-line device atomics +
// threadfence from 2048 blocks serialize catastrophically: 27.9us -> 90us).
__global__ __launch_bounds__(BLOCK) void row_ssq_kernel(
    const float* __restrict__ d, float* __restrict__ partials, int n) {
    const int wave = threadIdx.x >> 6;
    const int lane = threadIdx.x & 63;
    const int row  = blockIdx.x * WPB + wave;

    float acc = 0.0f;
    if (row < n) {
        const float4* __restrict__ p =
            reinterpret_cast<const float4*>(d + (size_t)row * K);
        // K/4 = 512 float4; 64 lanes -> 8 per lane. Explicit temporaries so
        // the compiler clusters all 8 global_load_dwordx4 before any waitcnt.
        float4 v0 = p[lane + 64 * 0];
        float4 v1 = p[lane + 64 * 1];
        float4 v2 = p[lane + 64 * 2];
        float4 v3 = p[lane + 64 * 3];
        float4 v4 = p[lane + 64 * 4];
        float4 v5 = p[lane + 64 * 5];
        float4 v6 = p[lane + 64 * 6];
        float4 v7 = p[lane + 64 * 7];

        float s0 = v0.x * v0.x + v0.y * v0.y + v0.z * v0.z + v0.w * v0.w;
        float s1 = v1.x * v1.x + v1.y * v1.y + v1.z * v1.z + v1.w * v1.w;
        float s2 = v2.x * v2.x + v2.y * v2.y + v2.z * v2.z + v2.w * v2.w;
        float s3 = v3.x * v3.x + v3.y * v3.y + v3.z * v3.z + v3.w * v3.w;
        s0 += v4.x * v4.x + v4.y * v4.y + v4.z * v4.z + v4.w * v4.w;
        s1 += v5.x * v5.x + v5.y * v5.y + v5.z * v5.z + v5.w * v5.w;
        s2 += v6.x * v6.x + v6.y * v6.y + v6.z * v6.z + v6.w * v6.w;
        s3 += v7.x * v7.x + v7.y * v7.y + v7.z * v7.z + v7.w * v7.w;
        float ssq = (s0 + s1) + (s2 + s3);

#pragma unroll
        for (int off = 32; off >= 1; off >>= 1)
            ssq += __shfl_xor(ssq, off);

        float t = ssq - 1.0f;
        acc = t * t;   // same value on all lanes; lane 0 publishes
    }

    __shared__ float smem[WPB];
    if (lane == 0) smem[wave] = acc;
    __syncthreads();
    if (threadIdx.x == 0)
        partials[blockIdx.x] = smem[0] + smem[1] + smem[2] + smem[3];
}

// Phase 2: one block reduces the partials, applies sqrt and scale.
__global__ __launch_bounds__(BLOCK) void finalize_kernel(
    const float* __restrict__ partials, int np, float* __restrict__ out) {
    float acc = 0.0f;
    for (int i = threadIdx.x; i < np; i += BLOCK) acc += partials[i];
#pragma unroll
    for (int off = 32; off >= 1; off >>= 1)
        acc += __shfl_xor(acc, off);

    __shared__ float smem[WPB];
    const int wave = threadIdx.x >> 6;
    const int lane = threadIdx.x & 63;
    if (lane == 0) smem[wave] = acc;
    __syncthreads();
    if (threadIdx.x == 0) {
        float t = 0.0f;
#pragma unroll
        for (int i = 0; i < WPB; ++i) t += smem[i];
        out[0] = 0.001f * sqrtf(t);
    }
}

extern "C" void kernel_launch(void* const* d_in, const int* in_sizes, int n_in,
                              void* d_out, int out_size, void* d_ws, size_t ws_size,
                              hipStream_t stream) {
    const float* d = (const float*)d_in[0];
    float* out = (float*)d_out;
    float* partials = (float*)d_ws;

    const int n = in_sizes[0] / K;            // 16384 rows
    const int grid = (n + WPB - 1) / WPB;     // 4096 blocks, 1 row per wave

    row_ssq_kernel<<<grid, BLOCK, 0, stream>>>(d, partials, n);
    finalize_kernel<<<1, BLOCK, 0, stream>>>(partials, grid, out);
}

// Round 4
// 27.706 us; speedup vs baseline: 3.2467x; 1.0758x over previous
//
#include <hip/hip_runtime.h>
#include <math.h>

#define BLOCK 256
#define WPB   (BLOCK / 64)     // 4 waves per block
#define K     2048
#define ROWS_PER_WAVE 4        // processed as 2 clustered pairs
#define GRID  1024             // 16384 rows / (4 waves * 4 rows)

// ssq of one float4
__device__ __forceinline__ float sq4(float4 v) {
    return v.x * v.x + v.y * v.y + v.z * v.z + v.w * v.w;
}

// Phase 1: each wave owns 4 adjacent rows, processed as two pairs.
// Each pair issues 16 float4 loads back-to-back (16-deep MLP) before any use.
__global__ __launch_bounds__(BLOCK) void row_ssq_kernel(
    const float* __restrict__ d, float* __restrict__ partials) {
    const int wave = threadIdx.x >> 6;
    const int lane = threadIdx.x & 63;
    const int base = (blockIdx.x * WPB + wave) * ROWS_PER_WAVE;

    float acc = 0.0f;
#pragma unroll
    for (int pair = 0; pair < 2; ++pair) {
        const float4* __restrict__ pa =
            reinterpret_cast<const float4*>(d + (size_t)(base + 2 * pair) * K);
        const float4* __restrict__ pb =
            reinterpret_cast<const float4*>(d + (size_t)(base + 2 * pair + 1) * K);
        // 16 loads clustered — all in flight before first waitcnt
        float4 a0 = pa[lane + 64 * 0], b0 = pb[lane + 64 * 0];
        float4 a1 = pa[lane + 64 * 1], b1 = pb[lane + 64 * 1];
        float4 a2 = pa[lane + 64 * 2], b2 = pb[lane + 64 * 2];
        float4 a3 = pa[lane + 64 * 3], b3 = pb[lane + 64 * 3];
        float4 a4 = pa[lane + 64 * 4], b4 = pb[lane + 64 * 4];
        float4 a5 = pa[lane + 64 * 5], b5 = pb[lane + 64 * 5];
        float4 a6 = pa[lane + 64 * 6], b6 = pb[lane + 64 * 6];
        float4 a7 = pa[lane + 64 * 7], b7 = pb[lane + 64 * 7];

        float sa = ((sq4(a0) + sq4(a1)) + (sq4(a2) + sq4(a3))) +
                   ((sq4(a4) + sq4(a5)) + (sq4(a6) + sq4(a7)));
        float sb = ((sq4(b0) + sq4(b1)) + (sq4(b2) + sq4(b3))) +
                   ((sq4(b4) + sq4(b5)) + (sq4(b6) + sq4(b7)));
#pragma unroll
        for (int off = 32; off >= 1; off >>= 1) {
            sa += __shfl_xor(sa, off);
            sb += __shfl_xor(sb, off);
        }
        float ta = sa - 1.0f, tb = sb - 1.0f;
        acc += ta * ta + tb * tb;
    }

    __shared__ float smem[WPB];
    if (lane == 0) smem[wave] = acc;
    __syncthreads();
    if (threadIdx.x == 0)
        partials[blockIdx.x] = smem[0] + smem[1] + smem[2] + smem[3];
}

// Phase 2: ONE wave, no LDS, no syncthreads. 1024 partials = 4 float4/lane.
__global__ __launch_bounds__(64) void finalize_kernel(
    const float* __restrict__ partials, float* __restrict__ out) {
    const int lane = threadIdx.x;
    const float4* __restrict__ p = reinterpret_cast<const float4*>(partials);
    float4 v0 = p[lane + 64 * 0];
    float4 v1 = p[lane + 64 * 1];
    float4 v2 = p[lane + 64 * 2];
    float4 v3 = p[lane + 64 * 3];
    float acc = ((v0.x + v0.y + v0.z + v0.w) + (v1.x + v1.y + v1.z + v1.w)) +
                ((v2.x + v2.y + v2.z + v2.w) + (v3.x + v3.y + v3.z + v3.w));
#pragma unroll
    for (int off = 32; off >= 1; off >>= 1)
        acc += __shfl_xor(acc, off);
    if (lane == 0) out[0] = 0.001f * sqrtf(acc);
}

extern "C" void kernel_launch(void* const* d_in, const int* in_sizes, int n_in,
                              void* d_out, int out_size, void* d_ws, size_t ws_size,
                              hipStream_t stream) {
    const float* d = (const float*)d_in[0];
    float* out = (float*)d_out;
    float* partials = (float*)d_ws;   // GRID floats

    row_ssq_kernel<<<GRID, BLOCK, 0, stream>>>(d, partials);
    finalize_kernel<<<1, 64, 0, stream>>>(partials, out);
}